// Round 1
// baseline (265.916 us; speedup 1.0000x reference)
//
#include <hip/hip_runtime.h>

#define C_  8
#define NQ_ 16
#define NK_ 32
#define B_  128
#define D_  128
#define E_  512
#define H_  8
#define A_  64
#define O_  64

typedef __attribute__((ext_vector_type(4))) float f32x4;
typedef __attribute__((ext_vector_type(8))) short bf16x8;

__device__ __forceinline__ short f2bf(float f) {
    union { float f; unsigned u; } v; v.f = f;
    unsigned r = v.u + 0x7fffu + ((v.u >> 16) & 1u);
    return (short)(r >> 16);
}

// ---------------------------------------------------------------------------
// Kernel 1: fused PE + per-(c,n) QKV projections.
// grid = 640 units * 4 e-blocks. Block: 256 thr = 4 waves, 128x128 out tile,
// K=128 in two 64-wide LDS stages. Wave computes 64x64 via 4x4 16x16x32 MFMAs.
// ---------------------------------------------------------------------------
__global__ __launch_bounds__(256) void qkv_proj_kernel(
    const float* __restrict__ qin, const float* __restrict__ kin,
    const float* __restrict__ Wq, const float* __restrict__ Wk,
    const float* __restrict__ Wv,
    short* __restrict__ wsq, short* __restrict__ wsk, short* __restrict__ wsv)
{
    __shared__ __align__(16) short Alds[B_][72];   // [row b][k], pad 64->72
    __shared__ __align__(16) short Blds[128][72];  // [e][k] (transposed W)
    __shared__ float pe_buf[D_];

    const int tid   = threadIdx.x;
    const int blk   = blockIdx.x;
    const int e_blk = blk & 3;
    const int unit  = blk >> 2;

    const float* X; const float* W; short* Y; int n;
    if (unit < C_ * NQ_) {
        n = unit % NQ_;
        X = qin + (size_t)unit * B_ * D_;
        W = Wq  + (size_t)unit * D_ * E_;
        Y = wsq + (size_t)unit * B_ * E_;
    } else if (unit < C_ * (NQ_ + NK_)) {
        const int u = unit - C_ * NQ_;
        n = u % NK_;
        X = kin + (size_t)u * B_ * D_;
        W = Wk  + (size_t)u * D_ * E_;
        Y = wsk + (size_t)u * B_ * E_;
    } else {
        const int u = unit - C_ * (NQ_ + NK_);
        n = u % NK_;
        X = kin + (size_t)u * B_ * D_;
        W = Wv  + (size_t)u * D_ * E_;
        Y = wsv + (size_t)u * B_ * E_;
    }

    // sinusoidal PE row for slot n (matches numpy float32 reference)
    if (tid < D_) {
        const int d = tid;
        const float freq = expf((float)(d & ~1) * (-9.210340371976184f / (float)D_));
        const float arg  = (float)n * freq;
        pe_buf[d] = (d & 1) ? cosf(arg) : sinf(arg);
    }
    __syncthreads();

    const int wv   = tid >> 6;
    const int lane = tid & 63;
    const int lr   = lane & 15;
    const int quad = lane >> 4;
    const int wrow = (wv >> 1) * 64;
    const int wcol = (wv & 1) * 64;

    f32x4 acc[4][4];
    for (int m = 0; m < 4; ++m)
        for (int nf = 0; nf < 4; ++nf)
            acc[m][nf] = (f32x4){0.f, 0.f, 0.f, 0.f};

    for (int k0 = 0; k0 < D_; k0 += 64) {
        // stage A tile: X + PE -> bf16, [128 b][64 k]
        {
            const int row  = tid >> 1;
            const int kseg = (tid & 1) * 32;
            const float* src = X + (size_t)row * D_ + k0 + kseg;
            for (int i = 0; i < 4; ++i) {
                bf16x8 v;
                for (int j = 0; j < 8; ++j)
                    v[j] = f2bf(src[i * 8 + j] + pe_buf[k0 + kseg + i * 8 + j]);
                *(bf16x8*)&Alds[row][kseg + i * 8] = v;
            }
        }
        // stage B tile transposed: Blds[e][k] <- W[k][e]
        {
            const int e  = tid & 127;
            const int kg = (tid >> 7) * 32;
            const float* src = W + (size_t)(k0 + kg) * E_ + e_blk * 128 + e;
            for (int i = 0; i < 4; ++i) {
                bf16x8 v;
                for (int j = 0; j < 8; ++j)
                    v[j] = f2bf(src[(size_t)(i * 8 + j) * E_]);
                *(bf16x8*)&Blds[e][kg + i * 8] = v;
            }
        }
        __syncthreads();

        for (int ks = 0; ks < 2; ++ks) {
            const int kc = ks * 32 + quad * 8;
            bf16x8 af[4], bf[4];
            for (int m = 0; m < 4; ++m)
                af[m] = *(const bf16x8*)&Alds[wrow + m * 16 + lr][kc];
            for (int nf = 0; nf < 4; ++nf)
                bf[nf] = *(const bf16x8*)&Blds[wcol + nf * 16 + lr][kc];
            for (int m = 0; m < 4; ++m)
                for (int nf = 0; nf < 4; ++nf)
                    acc[m][nf] = __builtin_amdgcn_mfma_f32_16x16x32_bf16(
                        af[m], bf[nf], acc[m][nf], 0, 0, 0);
        }
        __syncthreads();
    }

    // epilogue: bf16 store to (c,n,b,e) workspace
    for (int m = 0; m < 4; ++m)
        for (int nf = 0; nf < 4; ++nf)
            for (int r = 0; r < 4; ++r) {
                const int row = wrow + m * 16 + quad * 4 + r;
                const int col = e_blk * 128 + wcol + nf * 16 + lr;
                Y[(size_t)row * E_ + col] = f2bf(acc[m][nf][r]);
            }
}

// ---------------------------------------------------------------------------
// Kernel 2: attention. One wave per (c,b,h): S=QK^T (4 MFMA), softmax over 32
// keys (quad-local shfl reductions), P via LDS to A-layout, O=PV (4 MFMA).
// ---------------------------------------------------------------------------
__global__ __launch_bounds__(256) void attn_kernel(
    const short* __restrict__ wsq, const short* __restrict__ wsk,
    const short* __restrict__ wsv, short* __restrict__ wso)
{
    __shared__ __align__(16) short Plds[4][16][40];  // per-wave P, pad 32->40

    const int tid  = threadIdx.x;
    const int wv   = tid >> 6;
    const int lane = tid & 63;
    const int lr   = lane & 15;
    const int quad = lane >> 4;
    const int gw   = blockIdx.x * 4 + wv;     // 0..8191
    const int h = gw & (H_ - 1);
    const int b = (gw >> 3) & (B_ - 1);
    const int c = gw >> 10;

    // S = Q K^T  (M=16 q-slots, N=32 k-slots in 2 tiles, K=64 in 2 steps)
    f32x4 sacc[2];
    sacc[0] = (f32x4){0.f, 0.f, 0.f, 0.f};
    sacc[1] = (f32x4){0.f, 0.f, 0.f, 0.f};
    for (int ks = 0; ks < 2; ++ks) {
        const bf16x8 aq = *(const bf16x8*)(wsq +
            ((size_t)(c * NQ_ + lr) * B_ + b) * E_ + h * A_ + ks * 32 + quad * 8);
        for (int t = 0; t < 2; ++t) {
            const bf16x8 bk = *(const bf16x8*)(wsk +
                ((size_t)(c * NK_ + t * 16 + lr) * B_ + b) * E_ + h * A_ + ks * 32 + quad * 8);
            sacc[t] = __builtin_amdgcn_mfma_f32_16x16x32_bf16(aq, bk, sacc[t], 0, 0, 0);
        }
    }

    // softmax over the 32 keys of each q-row (row lives in one 16-lane quad)
    float p0[4], p1[4];
    for (int r = 0; r < 4; ++r) {
        const float v0 = sacc[0][r] * 0.125f;
        const float v1 = sacc[1][r] * 0.125f;
        float m = fmaxf(v0, v1);
        m = fmaxf(m, __shfl_xor(m, 1));
        m = fmaxf(m, __shfl_xor(m, 2));
        m = fmaxf(m, __shfl_xor(m, 4));
        m = fmaxf(m, __shfl_xor(m, 8));
        const float e0 = __expf(v0 - m);
        const float e1 = __expf(v1 - m);
        float s = e0 + e1;
        s += __shfl_xor(s, 1);
        s += __shfl_xor(s, 2);
        s += __shfl_xor(s, 4);
        s += __shfl_xor(s, 8);
        const float inv = 1.0f / s;
        p0[r] = e0 * inv;
        p1[r] = e1 * inv;
    }

    // P (C-layout) -> LDS -> A-layout
    for (int r = 0; r < 4; ++r) {
        Plds[wv][quad * 4 + r][lr]      = f2bf(p0[r]);
        Plds[wv][quad * 4 + r][16 + lr] = f2bf(p1[r]);
    }
    __syncthreads();
    const bf16x8 ap = *(const bf16x8*)&Plds[wv][lr][quad * 8];

    // O = P V  (N=64 in 4 tiles, K=32)
    const size_t vstride = (size_t)B_ * E_;
    const short* vb = wsv + ((size_t)(c * NK_ + quad * 8) * B_ + b) * E_ + h * A_;
    for (int t = 0; t < 4; ++t) {
        bf16x8 bvv;
        for (int j = 0; j < 8; ++j)
            bvv[j] = vb[(size_t)j * vstride + t * 16 + lr];
        f32x4 oacc = (f32x4){0.f, 0.f, 0.f, 0.f};
        oacc = __builtin_amdgcn_mfma_f32_16x16x32_bf16(ap, bvv, oacc, 0, 0, 0);
        for (int r = 0; r < 4; ++r)
            wso[((size_t)(c * NQ_ + quad * 4 + r) * B_ + b) * E_ + h * A_ + t * 16 + lr]
                = f2bf(oacc[r]);
    }
}

// ---------------------------------------------------------------------------
// Kernel 3: per-(c,q) output projection (128x64x512), 2 blocks per (c,q).
// ---------------------------------------------------------------------------
__global__ __launch_bounds__(256) void out_proj_kernel(
    const short* __restrict__ wso, const float* __restrict__ Wp,
    float* __restrict__ out)
{
    __shared__ __align__(16) short Xlds[64][72];
    __shared__ __align__(16) short Wlds[64][72];

    const int tid  = threadIdx.x;
    const int blk  = blockIdx.x;
    const int cq   = blk >> 1;
    const int half = blk & 1;

    const short* Xb = wso + (size_t)cq * B_ * E_ + (size_t)half * 64 * E_;
    const float* Wb = Wp  + (size_t)cq * E_ * O_;
    float*       Ob = out + (size_t)cq * B_ * O_ + (size_t)half * 64 * O_;

    const int wv   = tid >> 6;
    const int lane = tid & 63;
    const int lr   = lane & 15;
    const int quad = lane >> 4;

    f32x4 acc[4];
    for (int nf = 0; nf < 4; ++nf) acc[nf] = (f32x4){0.f, 0.f, 0.f, 0.f};

    for (int k0 = 0; k0 < E_; k0 += 64) {
        // stage X (already bf16): 64 rows x 64 k
        for (int i = 0; i < 2; ++i) {
            const int task = tid + 256 * i;
            const int row  = task >> 3;
            const int oct  = task & 7;
            *(bf16x8*)&Xlds[row][oct * 8] =
                *(const bf16x8*)(Xb + (size_t)row * E_ + k0 + oct * 8);
        }
        // stage Wp transposed: Wlds[o][e_rel] <- Wp[k0+e_rel][o]
        {
            const int o   = tid & 63;
            const int grp = tid >> 6;
            bf16x8 w0, w1;
            for (int j = 0; j < 8; ++j) {
                w0[j] = f2bf(Wb[(size_t)(k0 + grp * 16 + j)     * O_ + o]);
                w1[j] = f2bf(Wb[(size_t)(k0 + grp * 16 + 8 + j) * O_ + o]);
            }
            *(bf16x8*)&Wlds[o][grp * 16]     = w0;
            *(bf16x8*)&Wlds[o][grp * 16 + 8] = w1;
        }
        __syncthreads();

        for (int ks = 0; ks < 2; ++ks) {
            const int kc = ks * 32 + quad * 8;
            const bf16x8 af = *(const bf16x8*)&Xlds[wv * 16 + lr][kc];
            for (int nf = 0; nf < 4; ++nf) {
                const bf16x8 bf = *(const bf16x8*)&Wlds[nf * 16 + lr][kc];
                acc[nf] = __builtin_amdgcn_mfma_f32_16x16x32_bf16(af, bf, acc[nf], 0, 0, 0);
            }
        }
        __syncthreads();
    }

    for (int nf = 0; nf < 4; ++nf)
        for (int r = 0; r < 4; ++r)
            Ob[(size_t)(wv * 16 + quad * 4 + r) * O_ + nf * 16 + lr] = acc[nf][r];
}

extern "C" void kernel_launch(void* const* d_in, const int* in_sizes, int n_in,
                              void* d_out, int out_size, void* d_ws, size_t ws_size,
                              hipStream_t stream) {
    const float* q  = (const float*)d_in[0];
    const float* k  = (const float*)d_in[1];
    const float* Wq = (const float*)d_in[2];
    const float* Wk = (const float*)d_in[3];
    const float* Wv = (const float*)d_in[4];
    const float* Wp = (const float*)d_in[5];
    float* out = (float*)d_out;

    const size_t sz_q = (size_t)C_ * NQ_ * B_ * E_;  // 8,388,608
    const size_t sz_k = (size_t)C_ * NK_ * B_ * E_;  // 16,777,216
    short* wsq = (short*)d_ws;
    short* wsk = wsq + sz_q;
    short* wsv = wsk + sz_k;
    short* wso = wsv + sz_k;   // total ~100.7 MB of bf16 workspace

    qkv_proj_kernel<<<dim3(2560), dim3(256), 0, stream>>>(q, k, Wq, Wk, Wv, wsq, wsk, wsv);
    attn_kernel<<<dim3(2048), dim3(256), 0, stream>>>(wsq, wsk, wsv, wso);
    out_proj_kernel<<<dim3(256), dim3(256), 0, stream>>>(wso, Wp, out);
}

// Round 2
// 248.195 us; speedup vs baseline: 1.0714x; 1.0714x over previous
//
#include <hip/hip_runtime.h>

#define C_  8
#define NQ_ 16
#define NK_ 32
#define B_  128
#define D_  128
#define E_  512
#define H_  8
#define A_  64
#define O_  64

typedef __attribute__((ext_vector_type(4))) float f32x4;
typedef __attribute__((ext_vector_type(8))) short bf16x8;
typedef __attribute__((ext_vector_type(4))) short bf16x4;

__device__ __forceinline__ short f2bf(float f) {
    union { float f; unsigned u; } v; v.f = f;
    unsigned r = v.u + 0x7fffu + ((v.u >> 16) & 1u);
    return (short)(r >> 16);
}

// ---------------------------------------------------------------------------
// Kernel 1: fused PE + per-(c,n) QKV projections.
// grid = 640 units * 4 e-blocks, 256 thr. 128x128 out tile, K=128 in two
// 64-wide LDS stages. Register-first staging: all global loads issued before
// any convert to maximize memory-level parallelism.
// ---------------------------------------------------------------------------
__global__ __launch_bounds__(256) void qkv_proj_kernel(
    const float* __restrict__ qin, const float* __restrict__ kin,
    const float* __restrict__ Wq, const float* __restrict__ Wk,
    const float* __restrict__ Wv,
    short* __restrict__ wsq, short* __restrict__ wsk, short* __restrict__ wsv)
{
    __shared__ __align__(16) short Alds[B_][72];   // [row b][k], pad 64->72
    __shared__ __align__(16) short Blds[128][72];  // [e][k] (transposed W)
    __shared__ float pe_buf[D_];

    const int tid   = threadIdx.x;
    const int blk   = blockIdx.x;
    const int e_blk = blk & 3;
    const int unit  = blk >> 2;

    const float* X; const float* W; short* Y; int n;
    if (unit < C_ * NQ_) {
        n = unit % NQ_;
        X = qin + (size_t)unit * B_ * D_;
        W = Wq  + (size_t)unit * D_ * E_;
        Y = wsq + (size_t)unit * B_ * E_;
    } else if (unit < C_ * (NQ_ + NK_)) {
        const int u = unit - C_ * NQ_;
        n = u % NK_;
        X = kin + (size_t)u * B_ * D_;
        W = Wk  + (size_t)u * D_ * E_;
        Y = wsk + (size_t)u * B_ * E_;
    } else {
        const int u = unit - C_ * (NQ_ + NK_);
        n = u % NK_;
        X = kin + (size_t)u * B_ * D_;
        W = Wv  + (size_t)u * D_ * E_;
        Y = wsv + (size_t)u * B_ * E_;
    }

    if (tid < D_) {
        const int d = tid;
        const float freq = expf((float)(d & ~1) * (-9.210340371976184f / (float)D_));
        const float arg  = (float)n * freq;
        pe_buf[d] = (d & 1) ? cosf(arg) : sinf(arg);
    }
    __syncthreads();

    const int wv   = tid >> 6;
    const int lane = tid & 63;
    const int lr   = lane & 15;
    const int quad = lane >> 4;
    const int wrow = (wv >> 1) * 64;
    const int wcol = (wv & 1) * 64;

    f32x4 acc[4][4];
    for (int m = 0; m < 4; ++m)
        for (int nf = 0; nf < 4; ++nf)
            acc[m][nf] = (f32x4){0.f, 0.f, 0.f, 0.f};

    const int e  = tid & 127;
    const int kg = (tid >> 7) * 32;

    for (int k0 = 0; k0 < D_; k0 += 64) {
        // --- issue ALL global loads first (A: 8 float4 coalesced 1KB/instr;
        // --- B: 32 strided dwords, coalesced 256B/wave-instr) ---
        f32x4 a_raw[8];
        #pragma unroll
        for (int i = 0; i < 8; ++i) {
            const int id  = tid + 256 * i;
            const int row = id >> 4;
            const int ch  = id & 15;
            a_raw[i] = *(const f32x4*)(X + (size_t)row * D_ + k0 + ch * 4);
        }
        float b_raw[32];
        const float* bsrc = W + (size_t)(k0 + kg) * E_ + e_blk * 128 + e;
        #pragma unroll
        for (int i = 0; i < 32; ++i)
            b_raw[i] = bsrc[(size_t)i * E_];

        // --- convert A (+PE) and store (waits only on A's loads) ---
        #pragma unroll
        for (int i = 0; i < 8; ++i) {
            const int id  = tid + 256 * i;
            const int row = id >> 4;
            const int ch  = id & 15;
            bf16x4 v;
            #pragma unroll
            for (int j = 0; j < 4; ++j)
                v[j] = f2bf(a_raw[i][j] + pe_buf[k0 + ch * 4 + j]);
            *(bf16x4*)&Alds[row][ch * 4] = v;
        }
        // --- convert B and store transposed ---
        #pragma unroll
        for (int i = 0; i < 4; ++i) {
            bf16x8 v;
            #pragma unroll
            for (int j = 0; j < 8; ++j)
                v[j] = f2bf(b_raw[i * 8 + j]);
            *(bf16x8*)&Blds[e][kg + i * 8] = v;
        }
        __syncthreads();

        for (int ks = 0; ks < 2; ++ks) {
            const int kc = ks * 32 + quad * 8;
            bf16x8 af[4], bfr[4];
            for (int m = 0; m < 4; ++m)
                af[m] = *(const bf16x8*)&Alds[wrow + m * 16 + lr][kc];
            for (int nf = 0; nf < 4; ++nf)
                bfr[nf] = *(const bf16x8*)&Blds[wcol + nf * 16 + lr][kc];
            for (int m = 0; m < 4; ++m)
                for (int nf = 0; nf < 4; ++nf)
                    acc[m][nf] = __builtin_amdgcn_mfma_f32_16x16x32_bf16(
                        af[m], bfr[nf], acc[m][nf], 0, 0, 0);
        }
        __syncthreads();
    }

    for (int m = 0; m < 4; ++m)
        for (int nf = 0; nf < 4; ++nf)
            for (int r = 0; r < 4; ++r) {
                const int row = wrow + m * 16 + quad * 4 + r;
                const int col = e_blk * 128 + wcol + nf * 16 + lr;
                Y[(size_t)row * E_ + col] = f2bf(acc[m][nf][r]);
            }
}

// ---------------------------------------------------------------------------
// Kernel 2: attention. Block = (c, b, head-half): 4 waves, one head each.
// Q/K/V slices staged cooperatively into LDS with coalesced b128 row loads;
// all MFMA fragments read from LDS.
// ---------------------------------------------------------------------------
__global__ __launch_bounds__(256) void attn_kernel(
    const short* __restrict__ wsq, const short* __restrict__ wsk,
    const short* __restrict__ wsv, short* __restrict__ wso)
{
    __shared__ __align__(16) short Qs[16][264];   // 16 q-slots x 256 e (pad 8)
    __shared__ __align__(16) short Ks[32][264];
    __shared__ __align__(16) short Vs[32][258];   // u16 frag reads; b32 writes
    __shared__ __align__(16) short Ps[4][16][40]; // per-wave P

    const int tid = threadIdx.x;
    const int blk = blockIdx.x;              // ((c*B + b)*2 + hh)
    const int hh  = blk & 1;
    const int b   = (blk >> 1) & (B_ - 1);
    const int c   = blk >> 8;

    const size_t rowstride = (size_t)B_ * E_;
    const size_t ebase = (size_t)b * E_ + hh * 256;

    // ---- cooperative staging ----
    {
        const int nloc = tid >> 5;           // 0..7
        const int bi   = tid & 31;           // 16B block within 256-col row
        const short* qb = wsq + (size_t)c * NQ_ * rowstride + ebase + bi * 8;
        const short* kb = wsk + (size_t)c * NK_ * rowstride + ebase + bi * 8;
        const short* vb = wsv + (size_t)c * NK_ * rowstride + ebase + bi * 8;
        #pragma unroll
        for (int i = 0; i < 2; ++i) {
            const int nn = nloc + i * 8;
            *(bf16x8*)&Qs[nn][bi * 8] = *(const bf16x8*)(qb + (size_t)nn * rowstride);
        }
        #pragma unroll
        for (int i = 0; i < 4; ++i) {
            const int nn = nloc + i * 8;
            *(bf16x8*)&Ks[nn][bi * 8] = *(const bf16x8*)(kb + (size_t)nn * rowstride);
        }
        #pragma unroll
        for (int i = 0; i < 4; ++i) {
            const int nn = nloc + i * 8;
            bf16x8 v = *(const bf16x8*)(vb + (size_t)nn * rowstride);
            #pragma unroll
            for (int p = 0; p < 4; ++p)   // 4B-aligned packed writes (row pitch 516B)
                *(int*)&Vs[nn][bi * 8 + p * 2] = ((const int*)&v)[p];
        }
    }
    __syncthreads();

    const int wv   = tid >> 6;
    const int lane = tid & 63;
    const int lr   = lane & 15;
    const int quad = lane >> 4;
    const int lcol = wv * 64;                // this wave's head slice in LDS

    // ---- S = Q K^T ----
    f32x4 sacc0 = (f32x4){0.f, 0.f, 0.f, 0.f};
    f32x4 sacc1 = (f32x4){0.f, 0.f, 0.f, 0.f};
    #pragma unroll
    for (int ks = 0; ks < 2; ++ks) {
        const int kc = lcol + ks * 32 + quad * 8;
        const bf16x8 aq  = *(const bf16x8*)&Qs[lr][kc];
        const bf16x8 bk0 = *(const bf16x8*)&Ks[lr][kc];
        const bf16x8 bk1 = *(const bf16x8*)&Ks[16 + lr][kc];
        sacc0 = __builtin_amdgcn_mfma_f32_16x16x32_bf16(aq, bk0, sacc0, 0, 0, 0);
        sacc1 = __builtin_amdgcn_mfma_f32_16x16x32_bf16(aq, bk1, sacc1, 0, 0, 0);
    }

    // ---- softmax over 32 keys per q-row (row lives in one 16-lane quad) ----
    float p0[4], p1[4];
    for (int r = 0; r < 4; ++r) {
        const float v0 = sacc0[r] * 0.125f;
        const float v1 = sacc1[r] * 0.125f;
        float m = fmaxf(v0, v1);
        m = fmaxf(m, __shfl_xor(m, 1));
        m = fmaxf(m, __shfl_xor(m, 2));
        m = fmaxf(m, __shfl_xor(m, 4));
        m = fmaxf(m, __shfl_xor(m, 8));
        const float e0 = __expf(v0 - m);
        const float e1 = __expf(v1 - m);
        float s = e0 + e1;
        s += __shfl_xor(s, 1);
        s += __shfl_xor(s, 2);
        s += __shfl_xor(s, 4);
        s += __shfl_xor(s, 8);
        const float inv = 1.0f / s;
        p0[r] = e0 * inv;
        p1[r] = e1 * inv;
    }

    // ---- P (C-layout) -> LDS -> A-layout ----
    for (int r = 0; r < 4; ++r) {
        Ps[wv][quad * 4 + r][lr]      = f2bf(p0[r]);
        Ps[wv][quad * 4 + r][16 + lr] = f2bf(p1[r]);
    }
    __syncthreads();
    const bf16x8 ap = *(const bf16x8*)&Ps[wv][lr][quad * 8];

    // ---- O = P V ----
    #pragma unroll
    for (int t = 0; t < 4; ++t) {
        bf16x8 bvv;
        #pragma unroll
        for (int j = 0; j < 8; ++j)
            bvv[j] = Vs[quad * 8 + j][lcol + t * 16 + lr];
        f32x4 oacc = (f32x4){0.f, 0.f, 0.f, 0.f};
        oacc = __builtin_amdgcn_mfma_f32_16x16x32_bf16(ap, bvv, oacc, 0, 0, 0);
        for (int r = 0; r < 4; ++r)
            wso[((size_t)(c * NQ_ + quad * 4 + r) * B_ + b) * E_
                + hh * 256 + lcol + t * 16 + lr] = f2bf(oacc[r]);
    }
}

// ---------------------------------------------------------------------------
// Kernel 3: per-(c,q) output projection (128x64x512), 2 blocks per (c,q).
// Register-first Wp staging.
// ---------------------------------------------------------------------------
__global__ __launch_bounds__(256) void out_proj_kernel(
    const short* __restrict__ wso, const float* __restrict__ Wp,
    float* __restrict__ out)
{
    __shared__ __align__(16) short Xlds[64][72];
    __shared__ __align__(16) short Wlds[64][72];

    const int tid  = threadIdx.x;
    const int blk  = blockIdx.x;
    const int cq   = blk >> 1;
    const int half = blk & 1;

    const short* Xb = wso + (size_t)cq * B_ * E_ + (size_t)half * 64 * E_;
    const float* Wb = Wp  + (size_t)cq * E_ * O_;
    float*       Ob = out + (size_t)cq * B_ * O_ + (size_t)half * 64 * O_;

    const int wv   = tid >> 6;
    const int lane = tid & 63;
    const int lr   = lane & 15;
    const int quad = lane >> 4;

    f32x4 acc[4];
    for (int nf = 0; nf < 4; ++nf) acc[nf] = (f32x4){0.f, 0.f, 0.f, 0.f};

    const int o   = tid & 63;
    const int grp = tid >> 6;

    for (int k0 = 0; k0 < E_; k0 += 64) {
        // issue X loads first, then all 16 W dwords, then converts
        bf16x8 xv[2];
        #pragma unroll
        for (int i = 0; i < 2; ++i) {
            const int task = tid + 256 * i;
            const int row  = task >> 3;
            const int oct  = task & 7;
            xv[i] = *(const bf16x8*)(Xb + (size_t)row * E_ + k0 + oct * 8);
        }
        float wr[16];
        #pragma unroll
        for (int j = 0; j < 16; ++j)
            wr[j] = Wb[(size_t)(k0 + grp * 16 + j) * O_ + o];

        #pragma unroll
        for (int i = 0; i < 2; ++i) {
            const int task = tid + 256 * i;
            const int row  = task >> 3;
            const int oct  = task & 7;
            *(bf16x8*)&Xlds[row][oct * 8] = xv[i];
        }
        bf16x8 w0, w1;
        #pragma unroll
        for (int j = 0; j < 8; ++j) { w0[j] = f2bf(wr[j]); w1[j] = f2bf(wr[8 + j]); }
        *(bf16x8*)&Wlds[o][grp * 16]     = w0;
        *(bf16x8*)&Wlds[o][grp * 16 + 8] = w1;
        __syncthreads();

        for (int ks = 0; ks < 2; ++ks) {
            const int kc = ks * 32 + quad * 8;
            const bf16x8 af = *(const bf16x8*)&Xlds[wv * 16 + lr][kc];
            for (int nf = 0; nf < 4; ++nf) {
                const bf16x8 bfr = *(const bf16x8*)&Wlds[nf * 16 + lr][kc];
                acc[nf] = __builtin_amdgcn_mfma_f32_16x16x32_bf16(af, bfr, acc[nf], 0, 0, 0);
            }
        }
        __syncthreads();
    }

    for (int nf = 0; nf < 4; ++nf)
        for (int r = 0; r < 4; ++r)
            Ob[(size_t)(wv * 16 + quad * 4 + r) * O_ + nf * 16 + lr] = acc[nf][r];
}

extern "C" void kernel_launch(void* const* d_in, const int* in_sizes, int n_in,
                              void* d_out, int out_size, void* d_ws, size_t ws_size,
                              hipStream_t stream) {
    const float* q  = (const float*)d_in[0];
    const float* k  = (const float*)d_in[1];
    const float* Wq = (const float*)d_in[2];
    const float* Wk = (const float*)d_in[3];
    const float* Wv = (const float*)d_in[4];
    const float* Wp = (const float*)d_in[5];
    float* out = (float*)d_out;

    const size_t sz_q = (size_t)C_ * NQ_ * B_ * E_;
    const size_t sz_k = (size_t)C_ * NK_ * B_ * E_;
    short* wsq = (short*)d_ws;
    short* wsk = wsq + sz_q;
    short* wsv = wsk + sz_k;
    short* wso = wsv + sz_k;

    qkv_proj_kernel<<<dim3(2560), dim3(256), 0, stream>>>(q, k, Wq, Wk, Wv, wsq, wsk, wsv);
    attn_kernel<<<dim3(2048), dim3(256), 0, stream>>>(wsq, wsk, wsv, wso);
    out_proj_kernel<<<dim3(256), dim3(256), 0, stream>>>(wso, Wp, out);
}

// Round 3
// 246.728 us; speedup vs baseline: 1.0778x; 1.0059x over previous
//
#include <hip/hip_runtime.h>

#define C_  8
#define NQ_ 16
#define NK_ 32
#define B_  128
#define D_  128
#define E_  512
#define H_  8
#define A_  64
#define O_  64

typedef __attribute__((ext_vector_type(4))) float f32x4;
typedef __attribute__((ext_vector_type(8))) short bf16x8;
typedef __attribute__((ext_vector_type(4))) short bf16x4;

__device__ __forceinline__ short f2bf(float f) {
    union { float f; unsigned u; } v; v.f = f;
    unsigned r = v.u + 0x7fffu + ((v.u >> 16) & 1u);
    return (short)(r >> 16);
}

// ---------------------------------------------------------------------------
// Kernel 1: fused PE + per-(c,n) QKV projections.
// grid = 640 units * 4 e-blocks, 256 thr. 128x128 out tile, K=128 in two
// 64-wide LDS stages. Register-first staging. Output layout: (c, b, n, e)
// so the attention kernel's loads are contiguous.
// ---------------------------------------------------------------------------
__global__ __launch_bounds__(256) void qkv_proj_kernel(
    const float* __restrict__ qin, const float* __restrict__ kin,
    const float* __restrict__ Wq, const float* __restrict__ Wk,
    const float* __restrict__ Wv,
    short* __restrict__ wsq, short* __restrict__ wsk, short* __restrict__ wsv)
{
    __shared__ __align__(16) short Alds[B_][72];   // [row b][k], pad 64->72
    __shared__ __align__(16) short Blds[128][72];  // [e][k] (transposed W)
    __shared__ float pe_buf[D_];

    const int tid   = threadIdx.x;
    const int blk   = blockIdx.x;
    const int e_blk = blk & 3;
    const int unit  = blk >> 2;

    const float* X; const float* W; short* Y; int n; size_t ypitch;
    if (unit < C_ * NQ_) {
        const int c = unit >> 4;
        n = unit & 15;
        X = qin + (size_t)unit * B_ * D_;
        W = Wq  + (size_t)unit * D_ * E_;
        Y = wsq + (size_t)c * B_ * NQ_ * E_ + (size_t)n * E_;
        ypitch = (size_t)NQ_ * E_;
    } else if (unit < C_ * (NQ_ + NK_)) {
        const int u = unit - C_ * NQ_;
        const int c = u >> 5;
        n = u & 31;
        X = kin + (size_t)u * B_ * D_;
        W = Wk  + (size_t)u * D_ * E_;
        Y = wsk + (size_t)c * B_ * NK_ * E_ + (size_t)n * E_;
        ypitch = (size_t)NK_ * E_;
    } else {
        const int u = unit - C_ * (NQ_ + NK_);
        const int c = u >> 5;
        n = u & 31;
        X = kin + (size_t)u * B_ * D_;
        W = Wv  + (size_t)u * D_ * E_;
        Y = wsv + (size_t)c * B_ * NK_ * E_ + (size_t)n * E_;
        ypitch = (size_t)NK_ * E_;
    }

    if (tid < D_) {
        const int d = tid;
        const float freq = expf((float)(d & ~1) * (-9.210340371976184f / (float)D_));
        const float arg  = (float)n * freq;
        pe_buf[d] = (d & 1) ? cosf(arg) : sinf(arg);
    }
    __syncthreads();

    const int wv   = tid >> 6;
    const int lane = tid & 63;
    const int lr   = lane & 15;
    const int quad = lane >> 4;
    const int wrow = (wv >> 1) * 64;
    const int wcol = (wv & 1) * 64;

    f32x4 acc[4][4];
    for (int m = 0; m < 4; ++m)
        for (int nf = 0; nf < 4; ++nf)
            acc[m][nf] = (f32x4){0.f, 0.f, 0.f, 0.f};

    const int e  = tid & 127;
    const int kg = (tid >> 7) * 32;

    for (int k0 = 0; k0 < D_; k0 += 64) {
        f32x4 a_raw[8];
        #pragma unroll
        for (int i = 0; i < 8; ++i) {
            const int id  = tid + 256 * i;
            const int row = id >> 4;
            const int ch  = id & 15;
            a_raw[i] = *(const f32x4*)(X + (size_t)row * D_ + k0 + ch * 4);
        }
        float b_raw[32];
        const float* bsrc = W + (size_t)(k0 + kg) * E_ + e_blk * 128 + e;
        #pragma unroll
        for (int i = 0; i < 32; ++i)
            b_raw[i] = bsrc[(size_t)i * E_];

        #pragma unroll
        for (int i = 0; i < 8; ++i) {
            const int id  = tid + 256 * i;
            const int row = id >> 4;
            const int ch  = id & 15;
            bf16x4 v;
            #pragma unroll
            for (int j = 0; j < 4; ++j)
                v[j] = f2bf(a_raw[i][j] + pe_buf[k0 + ch * 4 + j]);
            *(bf16x4*)&Alds[row][ch * 4] = v;
        }
        #pragma unroll
        for (int i = 0; i < 4; ++i) {
            bf16x8 v;
            #pragma unroll
            for (int j = 0; j < 8; ++j)
                v[j] = f2bf(b_raw[i * 8 + j]);
            *(bf16x8*)&Blds[e][kg + i * 8] = v;
        }
        __syncthreads();

        for (int ks = 0; ks < 2; ++ks) {
            const int kc = ks * 32 + quad * 8;
            bf16x8 af[4], bfr[4];
            for (int m = 0; m < 4; ++m)
                af[m] = *(const bf16x8*)&Alds[wrow + m * 16 + lr][kc];
            for (int nf = 0; nf < 4; ++nf)
                bfr[nf] = *(const bf16x8*)&Blds[wcol + nf * 16 + lr][kc];
            for (int m = 0; m < 4; ++m)
                for (int nf = 0; nf < 4; ++nf)
                    acc[m][nf] = __builtin_amdgcn_mfma_f32_16x16x32_bf16(
                        af[m], bfr[nf], acc[m][nf], 0, 0, 0);
        }
        __syncthreads();
    }

    for (int m = 0; m < 4; ++m)
        for (int nf = 0; nf < 4; ++nf)
            for (int r = 0; r < 4; ++r) {
                const int row = wrow + m * 16 + quad * 4 + r;
                const int col = e_blk * 128 + wcol + nf * 16 + lr;
                Y[(size_t)row * ypitch + col] = f2bf(acc[m][nf][r]);
            }
}

// ---------------------------------------------------------------------------
// Kernel 2: attention. Block = (c, b, head-half). With the (c,b,n,e) layout
// every staging load is from an 80 KB contiguous region: row slices are
// 512 B contiguous at 1 KB pitch.
// ---------------------------------------------------------------------------
__global__ __launch_bounds__(256) void attn_kernel(
    const short* __restrict__ wsq, const short* __restrict__ wsk,
    const short* __restrict__ wsv, short* __restrict__ wso)
{
    __shared__ __align__(16) short Qs[16][264];
    __shared__ __align__(16) short Ks[32][264];
    __shared__ __align__(16) short Vs[32][258];
    __shared__ __align__(16) short Ps[4][16][40];

    const int tid = threadIdx.x;
    const int blk = blockIdx.x;              // ((c*B + b)*2 + hh)
    const int hh  = blk & 1;
    const int b   = (blk >> 1) & (B_ - 1);
    const int c   = blk >> 8;

    const short* qb = wsq + ((size_t)(c * B_ + b) * NQ_) * E_ + hh * 256;
    const short* kb = wsk + ((size_t)(c * B_ + b) * NK_) * E_ + hh * 256;
    const short* vb = wsv + ((size_t)(c * B_ + b) * NK_) * E_ + hh * 256;

    {
        const int nloc = tid >> 5;           // 0..7
        const int ch   = tid & 31;           // 16B chunk within 512B slice
        #pragma unroll
        for (int i = 0; i < 2; ++i) {
            const int nn = nloc + i * 8;
            *(bf16x8*)&Qs[nn][ch * 8] = *(const bf16x8*)(qb + (size_t)nn * E_ + ch * 8);
        }
        #pragma unroll
        for (int i = 0; i < 4; ++i) {
            const int nn = nloc + i * 8;
            *(bf16x8*)&Ks[nn][ch * 8] = *(const bf16x8*)(kb + (size_t)nn * E_ + ch * 8);
        }
        #pragma unroll
        for (int i = 0; i < 4; ++i) {
            const int nn = nloc + i * 8;
            bf16x8 v = *(const bf16x8*)(vb + (size_t)nn * E_ + ch * 8);
            #pragma unroll
            for (int p = 0; p < 4; ++p)
                *(int*)&Vs[nn][ch * 8 + p * 2] = ((const int*)&v)[p];
        }
    }
    __syncthreads();

    const int wv   = tid >> 6;
    const int lane = tid & 63;
    const int lr   = lane & 15;
    const int quad = lane >> 4;
    const int lcol = wv * 64;

    f32x4 sacc0 = (f32x4){0.f, 0.f, 0.f, 0.f};
    f32x4 sacc1 = (f32x4){0.f, 0.f, 0.f, 0.f};
    #pragma unroll
    for (int ks = 0; ks < 2; ++ks) {
        const int kc = lcol + ks * 32 + quad * 8;
        const bf16x8 aq  = *(const bf16x8*)&Qs[lr][kc];
        const bf16x8 bk0 = *(const bf16x8*)&Ks[lr][kc];
        const bf16x8 bk1 = *(const bf16x8*)&Ks[16 + lr][kc];
        sacc0 = __builtin_amdgcn_mfma_f32_16x16x32_bf16(aq, bk0, sacc0, 0, 0, 0);
        sacc1 = __builtin_amdgcn_mfma_f32_16x16x32_bf16(aq, bk1, sacc1, 0, 0, 0);
    }

    float p0[4], p1[4];
    for (int r = 0; r < 4; ++r) {
        const float v0 = sacc0[r] * 0.125f;
        const float v1 = sacc1[r] * 0.125f;
        float m = fmaxf(v0, v1);
        m = fmaxf(m, __shfl_xor(m, 1));
        m = fmaxf(m, __shfl_xor(m, 2));
        m = fmaxf(m, __shfl_xor(m, 4));
        m = fmaxf(m, __shfl_xor(m, 8));
        const float e0 = __expf(v0 - m);
        const float e1 = __expf(v1 - m);
        float s = e0 + e1;
        s += __shfl_xor(s, 1);
        s += __shfl_xor(s, 2);
        s += __shfl_xor(s, 4);
        s += __shfl_xor(s, 8);
        const float inv = 1.0f / s;
        p0[r] = e0 * inv;
        p1[r] = e1 * inv;
    }

    for (int r = 0; r < 4; ++r) {
        Ps[wv][quad * 4 + r][lr]      = f2bf(p0[r]);
        Ps[wv][quad * 4 + r][16 + lr] = f2bf(p1[r]);
    }
    __syncthreads();
    const bf16x8 ap = *(const bf16x8*)&Ps[wv][lr][quad * 8];

    #pragma unroll
    for (int t = 0; t < 4; ++t) {
        bf16x8 bvv;
        #pragma unroll
        for (int j = 0; j < 8; ++j)
            bvv[j] = Vs[quad * 8 + j][lcol + t * 16 + lr];
        f32x4 oacc = (f32x4){0.f, 0.f, 0.f, 0.f};
        oacc = __builtin_amdgcn_mfma_f32_16x16x32_bf16(ap, bvv, oacc, 0, 0, 0);
        for (int r = 0; r < 4; ++r)
            wso[((size_t)(c * NQ_ + quad * 4 + r) * B_ + b) * E_
                + hh * 256 + lcol + t * 16 + lr] = f2bf(oacc[r]);
    }
}

// ---------------------------------------------------------------------------
// Kernel 3: output projection. 512 blocks = (c,q) x B-half x O-half.
// K-step 64, cross-step register prefetch so each step's load latency hides
// under the previous step's convert/MFMA/barriers. 2 blocks/CU resident.
// ---------------------------------------------------------------------------
__global__ __launch_bounds__(256) void out_proj_kernel(
    const short* __restrict__ wso, const float* __restrict__ Wp,
    float* __restrict__ out)
{
    __shared__ __align__(16) short Xlds[64][72];
    __shared__ __align__(16) short Wlds[32][72];

    const int tid = threadIdx.x;
    const int blk = blockIdx.x;
    const int cq  = blk >> 2;
    const int bh  = (blk >> 1) & 1;
    const int oh  = blk & 1;

    const short* Xb = wso + (size_t)cq * B_ * E_ + (size_t)bh * 64 * E_;
    const float* Wb = Wp  + (size_t)cq * E_ * O_ + oh * 32;
    float*       Ob = out + (size_t)cq * B_ * O_ + (size_t)bh * 64 * O_ + oh * 32;

    const int wv   = tid >> 6;
    const int lane = tid & 63;
    const int lr   = lane & 15;
    const int quad = lane >> 4;
    const int o    = tid & 31;
    const int kg   = tid >> 5;   // 0..7

    f32x4 acc[2];
    acc[0] = (f32x4){0.f, 0.f, 0.f, 0.f};
    acc[1] = (f32x4){0.f, 0.f, 0.f, 0.f};

    bf16x8 xv[2][2];
    float  wr[2][8];

    auto issue = [&](int s, int buf) {
        const int k0 = s * 64;
        #pragma unroll
        for (int i = 0; i < 2; ++i) {
            const int task = tid + 256 * i;
            xv[buf][i] = *(const bf16x8*)(Xb + (size_t)(task >> 3) * E_ + k0 + (task & 7) * 8);
        }
        #pragma unroll
        for (int j = 0; j < 8; ++j)
            wr[buf][j] = Wb[(size_t)(k0 + kg * 8 + j) * O_ + o];
    };

    issue(0, 0);
    #pragma unroll
    for (int s = 0; s < 8; ++s) {
        const int cb = s & 1;
        if (s < 7) issue(s + 1, cb ^ 1);

        #pragma unroll
        for (int i = 0; i < 2; ++i) {
            const int task = tid + 256 * i;
            *(bf16x8*)&Xlds[task >> 3][(task & 7) * 8] = xv[cb][i];
        }
        bf16x8 wv8;
        #pragma unroll
        for (int j = 0; j < 8; ++j) wv8[j] = f2bf(wr[cb][j]);
        *(bf16x8*)&Wlds[o][kg * 8] = wv8;
        __syncthreads();

        #pragma unroll
        for (int ks = 0; ks < 2; ++ks) {
            const int kc = ks * 32 + quad * 8;
            const bf16x8 af = *(const bf16x8*)&Xlds[wv * 16 + lr][kc];
            #pragma unroll
            for (int nf = 0; nf < 2; ++nf) {
                const bf16x8 bfr = *(const bf16x8*)&Wlds[nf * 16 + lr][kc];
                acc[nf] = __builtin_amdgcn_mfma_f32_16x16x32_bf16(af, bfr, acc[nf], 0, 0, 0);
            }
        }
        __syncthreads();
    }

    #pragma unroll
    for (int nf = 0; nf < 2; ++nf)
        for (int r = 0; r < 4; ++r)
            Ob[(size_t)(wv * 16 + quad * 4 + r) * O_ + nf * 16 + lr] = acc[nf][r];
}

extern "C" void kernel_launch(void* const* d_in, const int* in_sizes, int n_in,
                              void* d_out, int out_size, void* d_ws, size_t ws_size,
                              hipStream_t stream) {
    const float* q  = (const float*)d_in[0];
    const float* k  = (const float*)d_in[1];
    const float* Wq = (const float*)d_in[2];
    const float* Wk = (const float*)d_in[3];
    const float* Wv = (const float*)d_in[4];
    const float* Wp = (const float*)d_in[5];
    float* out = (float*)d_out;

    const size_t sz_q = (size_t)C_ * NQ_ * B_ * E_;
    const size_t sz_k = (size_t)C_ * NK_ * B_ * E_;
    short* wsq = (short*)d_ws;
    short* wsk = wsq + sz_q;
    short* wsv = wsk + sz_k;
    short* wso = wsv + sz_k;

    qkv_proj_kernel<<<dim3(2560), dim3(256), 0, stream>>>(q, k, Wq, Wk, Wv, wsq, wsk, wsv);
    attn_kernel<<<dim3(2048), dim3(256), 0, stream>>>(wsq, wsk, wsv, wso);
    out_proj_kernel<<<dim3(512), dim3(256), 0, stream>>>(wso, Wp, out);
}